// Round 4
// baseline (213.885 us; speedup 1.0000x reference)
//
#include <hip/hip_runtime.h>

typedef _Float16 half_t;

#define OUTS 7
#define NORI 8
#define NCH  256
#define FH   128
#define FW   128
#define HW   (FH * FW)
#define NSAMP (2 * OUTS * 2 * OUTS)  // 196
#define NBIN  (OUTS * OUTS)          // 49

struct __align__(32) Geom { int o[4]; float w[4]; };

// ---------------- transpose [N,C,H,W] f32 -> [N,H,W,C] f16 ----------------
__global__ __launch_bounds__(256) void transpose_nchw_nhwc_h(
    const float* __restrict__ in, half_t* __restrict__ out) {
  __shared__ float tile[64][65];
  const int b  = blockIdx.z;
  const int p0 = blockIdx.x * 64;
  const int c0 = blockIdx.y * 64;
  const int tx = threadIdx.x & 63;
  const int ty = threadIdx.x >> 6;

  const float* src = in + ((size_t)b * NCH + c0) * HW + p0;
#pragma unroll
  for (int i = 0; i < 16; ++i) {
    int c = ty + i * 4;
    tile[c][tx] = src[(size_t)c * HW + tx];
  }
  __syncthreads();
  half_t* dst = out + ((size_t)b * HW + p0) * NCH + c0;
#pragma unroll
  for (int i = 0; i < 16; ++i) {
    int p = ty + i * 4;
    dst[(size_t)p * NCH + tx] = (half_t)tile[tx][p];
  }
}

// ---------------- geometry precompute: one (roi, sample) per thread ------
// Buffer layout: g[r*196 + bin*4 + sub], sub = iy*2 + ix. Byte offsets with
// batch base folded in; weights pre-scaled by 0.25 (the 2x2 sample mean).
__global__ __launch_bounds__(256) void geom_kernel(
    const float* __restrict__ rois, Geom* __restrict__ g, int total) {
  const int gid = blockIdx.x * 256 + threadIdx.x;
  if (gid >= total) return;
  const int r   = gid / NSAMP;
  const int q   = gid - r * NSAMP;
  const int bin = q >> 2;
  const int sub = q & 3;
  const int by = bin / OUTS, bx = bin - by * OUTS;
  const int py = by * 2 + (sub >> 1);
  const int px = bx * 2 + (sub & 1);

  const float* roi = rois + (size_t)r * 6;
  const int   b     = (int)roi[0];
  const float cx    = roi[1] * 0.25f;
  const float cy    = roi[2] * 0.25f;
  const float rw    = fmaxf(roi[3] * 0.25f, 1.0f);
  const float rh    = fmaxf(roi[4] * 0.25f, 1.0f);
  const float theta = roi[5];
  const float bin_w = rw * (1.0f / OUTS);
  const float bin_h = rh * (1.0f / OUTS);
  const float ct = cosf(theta), st = sinf(theta);
  const float hbw = 0.5f * bin_w, hbh = 0.5f * bin_h;
  const float xoff = 0.25f * bin_w - 0.5f * rw;
  const float yoff = 0.25f * bin_h - 0.5f * rh;

  const float yy = (float)py * hbh + yoff;
  const float xx = (float)px * hbw + xoff;
  const float x = xx * ct + yy * st + cx;
  const float y = yy * ct - xx * st + cy;

  Geom gg;
  gg.o[0] = gg.o[1] = gg.o[2] = gg.o[3] = 0;
  gg.w[0] = gg.w[1] = gg.w[2] = gg.w[3] = 0.f;
  if (x > -1.0f && x < (float)FW && y > -1.0f && y < (float)FH) {
    float xc = fmaxf(x, 0.f);
    float yc = fmaxf(y, 0.f);
    int x0 = (int)xc;
    int y0 = (int)yc;
    int x1, y1;
    float lx, ly;
    if (x0 >= FW - 1) { x0 = FW - 1; x1 = FW - 1; lx = 0.f; }
    else              { x1 = x0 + 1; lx = xc - (float)x0; }
    if (y0 >= FH - 1) { y0 = FH - 1; y1 = FH - 1; ly = 0.f; }
    else              { y1 = y0 + 1; ly = yc - (float)y0; }
    const float wx0 = 1.f - lx, wy0 = 1.f - ly;
    gg.w[0] = 0.25f * wy0 * wx0; gg.w[1] = 0.25f * wy0 * lx;
    gg.w[2] = 0.25f * ly  * wx0; gg.w[3] = 0.25f * ly  * lx;
    const int base = b * HW;
    // byte offset = element * NCH * sizeof(half) = element << 9
    gg.o[0] = (base + y0 * FW + x0) << 9; gg.o[1] = (base + y0 * FW + x1) << 9;
    gg.o[2] = (base + y1 * FW + x0) << 9; gg.o[3] = (base + y1 * FW + x1) << 9;
  }
  g[gid] = gg;
}

// ---------------- main kernel: SGPR geometry, fp16 CL features -----------
__global__ __launch_bounds__(256) void riroi_main(
    const half_t* __restrict__ feat, const float* __restrict__ rois,
    const Geom* __restrict__ geom, float* __restrict__ out) {
  __shared__ alignas(16) float s_tr[NCH * NBIN];  // 49 KB

  const int r = blockIdx.x;
  const int c = threadIdx.x;

  const float theta = rois[(size_t)r * 6 + 5];  // uniform
  const float indf = theta * (8.0f / 6.2831853071795862f);
  const float ind0 = floorf(indf);
  const float l    = indf - ind0;
  const int   ind  = ((int)ind0) & 7;  // ind0 in [0,8)
  const int   o    = c & 7;
  const int   lane = c & 63;
  const int srcLane  = (lane & 56) | ((o - ind + 8) & 7);
  const int srcLane2 = (lane & 56) | ((o - ind + 9) & 7);

  const Geom* gp = geom + (size_t)r * NSAMP;
  const char* fb = (const char*)feat;
  const int c2 = c * 2;

#pragma unroll
  for (int bin = 0; bin < NBIN; ++bin) {
    float a = 0.f;
#pragma unroll
    for (int t = 0; t < 4; ++t) {
      const Geom gg = gp[bin * 4 + t];  // uniform -> s_load
      const int o0 = __builtin_amdgcn_readfirstlane(gg.o[0]);
      const int o1 = __builtin_amdgcn_readfirstlane(gg.o[1]);
      const int o2 = __builtin_amdgcn_readfirstlane(gg.o[2]);
      const int o3 = __builtin_amdgcn_readfirstlane(gg.o[3]);
      a += gg.w[0] * (float)*(const half_t*)(fb + o0 + c2)
         + gg.w[1] * (float)*(const half_t*)(fb + o1 + c2)
         + gg.w[2] * (float)*(const half_t*)(fb + o2 + c2)
         + gg.w[3] * (float)*(const half_t*)(fb + o3 + c2);
    }
    // orientation mix inline (groups of 8 channels within a wave)
    const float vs = __shfl(a, srcLane, 64);
    const float vp = __shfl(a, srcLane2, 64);
    s_tr[c * NBIN + bin] = vs + l * (vp - vs);
  }
  __syncthreads();

  // fully coalesced store of the whole roi's [256][49] block
  const float4* s4 = (const float4*)s_tr;
  float4* d4 = (float4*)(out + (size_t)r * (NCH * NBIN));
#pragma unroll
  for (int i = 0; i < 13; ++i) {
    int idx = c + i * 256;
    if (idx < NCH * NBIN / 4) d4[idx] = s4[idx];
  }
}

// ---------------- tier-2 fallback: R3 kernel (LDS geometry) --------------
__global__ __launch_bounds__(256) void riroi_cl_h(
    const half_t* __restrict__ feat, const float* __restrict__ rois,
    float* __restrict__ out) {
  __shared__ int4   s_off[NSAMP];
  __shared__ float4 s_w[NSAMP];
  __shared__ alignas(16) float s_tr[64 * NBIN];

  const int r = blockIdx.x;
  const int c = threadIdx.x;
  const float* roi = rois + (size_t)r * 6;
  const int   b     = (int)roi[0];
  const float theta = roi[5];

  if (c < NSAMP) {
    const float cx = roi[1] * 0.25f;
    const float cy = roi[2] * 0.25f;
    const float rw = fmaxf(roi[3] * 0.25f, 1.0f);
    const float rh = fmaxf(roi[4] * 0.25f, 1.0f);
    const float bin_w = rw * (1.0f / OUTS);
    const float bin_h = rh * (1.0f / OUTS);
    const float ct = cosf(theta), st = sinf(theta);
    const float hbw = 0.5f * bin_w, hbh = 0.5f * bin_h;
    const float xoff = 0.25f * bin_w - 0.5f * rw;
    const float yoff = 0.25f * bin_h - 0.5f * rh;
    const int py = c / (2 * OUTS);
    const int px = c - py * (2 * OUTS);
    const float yy = (float)py * hbh + yoff;
    const float xx = (float)px * hbw + xoff;
    const float x = xx * ct + yy * st + cx;
    const float y = yy * ct - xx * st + cy;
    int4   o4 = {0, 0, 0, 0};
    float4 w4 = {0.f, 0.f, 0.f, 0.f};
    if (x > -1.0f && x < (float)FW && y > -1.0f && y < (float)FH) {
      float xc = fmaxf(x, 0.f), yc = fmaxf(y, 0.f);
      int x0 = (int)xc, y0 = (int)yc, x1, y1;
      float lx, ly;
      if (x0 >= FW - 1) { x0 = FW - 1; x1 = FW - 1; lx = 0.f; }
      else              { x1 = x0 + 1; lx = xc - (float)x0; }
      if (y0 >= FH - 1) { y0 = FH - 1; y1 = FH - 1; ly = 0.f; }
      else              { y1 = y0 + 1; ly = yc - (float)y0; }
      const float wx0 = 1.f - lx, wy0 = 1.f - ly;
      w4.x = wy0 * wx0; w4.y = wy0 * lx; w4.z = ly * wx0; w4.w = ly * lx;
      o4.x = (y0 * FW + x0) * NCH; o4.y = (y0 * FW + x1) * NCH;
      o4.z = (y1 * FW + x0) * NCH; o4.w = (y1 * FW + x1) * NCH;
    }
    s_off[c] = o4;
    s_w[c]   = w4;
  }
  __syncthreads();

  const half_t* fbb = feat + (size_t)b * (NCH * HW) + c;
  float acc[NBIN];
#pragma unroll
  for (int i = 0; i < NBIN; ++i) acc[i] = 0.f;
#pragma unroll
  for (int py = 0; py < 2 * OUTS; ++py) {
#pragma unroll
    for (int px = 0; px < 2 * OUTS; ++px) {
      const int s = py * (2 * OUTS) + px;
      const int bin = (py >> 1) * OUTS + (px >> 1);
      const int4   o = s_off[s];
      const float4 w = s_w[s];
      acc[bin] += w.x * (float)fbb[o.x] + w.y * (float)fbb[o.y]
                + w.z * (float)fbb[o.z] + w.w * (float)fbb[o.w];
    }
  }
#pragma unroll
  for (int i = 0; i < NBIN; ++i) acc[i] *= 0.25f;

  const float indf = (theta * 8.0f) / 6.2831853071795862f;
  const float ind0 = floorf(indf);
  const float l    = indf - ind0;
  const int   ind  = ((int)ind0) % NORI;
  const int   o    = c & 7;
  const int   lane = c & 63;
  const int srcLane  = (lane & 56) | ((o - ind + 8) & 7);
  const int srcLane2 = (lane & 56) | ((o - ind + 9) & 7);
#pragma unroll
  for (int i = 0; i < NBIN; ++i) {
    const float v  = acc[i];
    const float vs = __shfl(v, srcLane, 64);
    const float vp = __shfl(v, srcLane2, 64);
    acc[i] = (1.f - l) * vs + l * vp;
  }
  const int grp = c >> 6;
#pragma unroll
  for (int g = 0; g < 4; ++g) {
    if (grp == g) {
#pragma unroll
      for (int i = 0; i < NBIN; ++i) s_tr[(c & 63) * NBIN + i] = acc[i];
    }
    __syncthreads();
    const float4* s4 = (const float4*)s_tr;
    float4* d4 = (float4*)(out + ((size_t)r * NCH + g * 64) * NBIN);
#pragma unroll
    for (int i = 0; i < 4; ++i) {
      int idx = c + i * 256;
      if (idx < 64 * NBIN / 4) d4[idx] = s4[idx];
    }
    __syncthreads();
  }
}

// ---------------- tier-3 fallback: fp32 NCHW direct ----------------------
__global__ __launch_bounds__(256) void riroi_cf(
    const float* __restrict__ feat, const float* __restrict__ rois,
    float* __restrict__ out) {
  const int r = blockIdx.x;
  const int c = threadIdx.x;
  const float* roi = rois + (size_t)r * 6;
  const int   b     = (int)roi[0];
  const float cx    = roi[1] * 0.25f;
  const float cy    = roi[2] * 0.25f;
  const float rw    = fmaxf(roi[3] * 0.25f, 1.0f);
  const float rh    = fmaxf(roi[4] * 0.25f, 1.0f);
  const float theta = roi[5];
  const float bin_w = rw * (1.0f / OUTS), bin_h = rh * (1.0f / OUTS);
  const float ct = cosf(theta), st = sinf(theta);
  const float hbw = 0.5f * bin_w, hbh = 0.5f * bin_h;
  const float xoff = 0.25f * bin_w - 0.5f * rw;
  const float yoff = 0.25f * bin_h - 0.5f * rh;
  const float* fb = feat + ((size_t)b * NCH + c) * HW;
  float acc[NBIN];
#pragma unroll
  for (int i = 0; i < NBIN; ++i) acc[i] = 0.f;
  for (int py = 0; py < 2 * OUTS; ++py) {
    const float yy = (float)py * hbh + yoff;
    for (int px = 0; px < 2 * OUTS; ++px) {
      const float xx = (float)px * hbw + xoff;
      const float x = xx * ct + yy * st + cx;
      const float y = yy * ct - xx * st + cy;
      if (x > -1.0f && x < (float)FW && y > -1.0f && y < (float)FH) {
        float xc = fmaxf(x, 0.f), yc = fmaxf(y, 0.f);
        int x0 = (int)xc, y0 = (int)yc, x1, y1;
        float lx, ly;
        if (x0 >= FW - 1) { x0 = FW - 1; x1 = FW - 1; lx = 0.f; }
        else              { x1 = x0 + 1; lx = xc - (float)x0; }
        if (y0 >= FH - 1) { y0 = FH - 1; y1 = FH - 1; ly = 0.f; }
        else              { y1 = y0 + 1; ly = yc - (float)y0; }
        const float wx0 = 1.f - lx, wy0 = 1.f - ly;
        acc[(py >> 1) * OUTS + (px >> 1)] +=
            (wy0 * wx0) * fb[y0 * FW + x0] + (wy0 * lx) * fb[y0 * FW + x1]
          + (ly * wx0) * fb[y1 * FW + x0] + (ly * lx) * fb[y1 * FW + x1];
      }
    }
  }
#pragma unroll
  for (int i = 0; i < NBIN; ++i) acc[i] *= 0.25f;
  const float indf = (theta * 8.0f) / 6.2831853071795862f;
  const float ind0 = floorf(indf);
  const float l    = indf - ind0;
  const int   ind  = ((int)ind0) % NORI;
  const int   o    = c & 7;
  const int   lane = c & 63;
  const int srcLane  = (lane & 56) | ((o - ind + 8) & 7);
  const int srcLane2 = (lane & 56) | ((o - ind + 9) & 7);
  float* op = out + ((size_t)r * NCH + c) * NBIN;
#pragma unroll
  for (int i = 0; i < NBIN; ++i) {
    const float v  = acc[i];
    const float vs = __shfl(v, srcLane, 64);
    const float vp = __shfl(v, srcLane2, 64);
    op[i] = (1.f - l) * vs + l * vp;
  }
}

extern "C" void kernel_launch(void* const* d_in, const int* in_sizes, int n_in,
                              void* d_out, int out_size, void* d_ws, size_t ws_size,
                              hipStream_t stream) {
  const float* feat = (const float*)d_in[0];
  const float* rois = (const float*)d_in[1];
  float* out = (float*)d_out;
  const int R = in_sizes[1] / 6;
  const int N = in_sizes[0] / (NCH * HW);

  const size_t geom_bytes = (size_t)R * NSAMP * sizeof(Geom);
  const size_t feat_bytes = (size_t)N * HW * NCH * sizeof(half_t);

  if (ws_size >= geom_bytes + feat_bytes) {
    Geom*   g  = (Geom*)d_ws;
    half_t* ft = (half_t*)((char*)d_ws + geom_bytes);
    dim3 tg(HW / 64, NCH / 64, N);
    transpose_nchw_nhwc_h<<<tg, 256, 0, stream>>>(feat, ft);
    const int total = R * NSAMP;
    geom_kernel<<<(total + 255) / 256, 256, 0, stream>>>(rois, g, total);
    riroi_main<<<R, 256, 0, stream>>>(ft, rois, g, out);
  } else if (ws_size >= feat_bytes) {
    half_t* ft = (half_t*)d_ws;
    dim3 tg(HW / 64, NCH / 64, N);
    transpose_nchw_nhwc_h<<<tg, 256, 0, stream>>>(feat, ft);
    riroi_cl_h<<<R, 256, 0, stream>>>(ft, rois, out);
  } else {
    riroi_cf<<<R, 256, 0, stream>>>(feat, rois, out);
  }
}